// Round 4
// baseline (338.199 us; speedup 1.0000x reference)
//
#include <hip/hip_runtime.h>
#include <math.h>

#define N_HEADS 8
#define HEAD_DIM 16
#define HID 128
// qkv row: 256B q (bf16) + 16 x [8B k fp8 | 8B v fp8] = 512B
#define QKV_ROWB 512

typedef unsigned short ushort_t;
typedef __attribute__((ext_vector_type(8))) short short8;
typedef __attribute__((ext_vector_type(4))) float floatx4;
typedef __attribute__((ext_vector_type(2))) float f32x2;

#define KV_SCALE 64.0f
#define KV_INV_SCALE 0.015625f

__device__ __forceinline__ ushort_t f2bf(float f) {
    unsigned u = __float_as_uint(f);
    unsigned r = (u + 0x7FFFu + ((u >> 16) & 1u)) >> 16;
    return (ushort_t)r;
}
__device__ __forceinline__ float bf2f(ushort_t u) {
    return __uint_as_float(((unsigned)u) << 16);
}

__device__ __forceinline__ void gld_lds16(const void* g, void* l) {
    __builtin_amdgcn_global_load_lds(
        (const __attribute__((address_space(1))) void*)g,
        (__attribute__((address_space(3))) void*)l, 16, 0, 0);
}

// fast exact-GELU: erf via Abramowitz-Stegun 7.1.26 (|err| <= 1.5e-7)
__device__ __forceinline__ float gelu_f(float x) {
    float z = fabsf(x) * 0.70710678118654752f;
    float t = 1.0f / (1.0f + 0.3275911f * z);
    float y = t * (0.254829592f + t * (-0.284496736f + t * (1.421413741f
            + t * (-1.453152027f + t * 1.061405429f))));
    float e = 1.0f - y * __expf(-z * z);
    e = copysignf(e, x);
    return 0.5f * x * (1.0f + e);
}

// ---- prep kernel: cvt x, cvt 6 weights, pack qkv bias, count dst degrees ----
__global__ __launch_bounds__(256)
void prep_kernel(const float* __restrict__ x,
                 const float* __restrict__ Wq, const float* __restrict__ Wk,
                 const float* __restrict__ Wv, const float* __restrict__ Wo,
                 const float* __restrict__ W1, const float* __restrict__ W2,
                 const float* __restrict__ bq, const float* __restrict__ bk,
                 const float* __restrict__ bv,
                 const int* __restrict__ dst, int* __restrict__ cnt, int E,
                 ushort_t* __restrict__ xb, ushort_t* __restrict__ wts,
                 float* __restrict__ bqkv, int xpairs)
{
    int i = blockIdx.x * 256 + threadIdx.x;
    if (i < xpairs) {
        float2 v = ((const float2*)x)[i];
        xb[i * 2]     = f2bf(v.x);
        xb[i * 2 + 1] = f2bf(v.y);
        return;
    }
    int j = i - xpairs;
    if (j < 98304) {
        const float* s; int off;
        if (j < 32768) {
            if (j < 8192)       { s = Wq; off = j; }
            else if (j < 16384) { s = Wk; off = j - 8192; }
            else if (j < 24576) { s = Wv; off = j - 16384; }
            else                { s = Wo; off = j - 24576; }
        } else if (j < 65536)   { s = W1; off = j - 32768; }
        else                    { s = W2; off = j - 65536; }
        float2 v = ((const float2*)s)[off];
        wts[j * 2]     = f2bf(v.x);
        wts[j * 2 + 1] = f2bf(v.y);
        return;
    }
    int b = j - 98304;
    if (b < 384) {
        bqkv[b] = (b < 128) ? bq[b] : (b < 256) ? bk[b - 128] : bv[b - 256];
        return;
    }
    int e = b - 384;
    if (e < E) atomicAdd(&cnt[dst[e]], 1);
}

// ---------------- templated bf16 MFMA GEMM (MT=64) --------------------------
// Double-buffered K-panels: stage(kc+1) issued BEFORE MFMA(kc) so the loads
// fly under compute; single barrier per K-step.
// OUTF: 0 = bf16 out, 1 = f32 out, 2 = fp8 kv out,
//       3 = merged QKV: y==0 -> bf16 q (ostride 256), y==1/2 -> fp8 k/v.
template<int MT, int ACT, int LN, int OUTF>
__global__ __launch_bounds__(256)
void gemm_t(const ushort_t* __restrict__ A, int lda, int M,
            const ushort_t* __restrict__ W, int K,
            const float* __restrict__ bias,
            float* __restrict__ outf, ushort_t* __restrict__ outb, int ostride,
            const float* __restrict__ resf, const ushort_t* __restrict__ resb,
            const float* __restrict__ g, const float* __restrict__ be)
{
    constexpr int MI   = MT / 32;
    constexpr int HALF = MT * 64 + 128 * 64;
    constexpr int BNC  = MT * 136;
    constexpr int SB   = (2 * HALF > BNC) ? 2 * HALF : BNC;
    __shared__ __align__(16) ushort_t sbuf[SB];
    __shared__ float pS[LN ? MT : 1][2];
    __shared__ float pQ[LN ? MT : 1][2];

    const int tid  = threadIdx.x;
    const int wave = tid >> 6, lane = tid & 63;
    const int gm0 = blockIdx.x * MT;
    const int o0  = blockIdx.y * 128;
    const int mhalf = wave >> 1, ohalf = wave & 1;

    auto stage = [&](int kc, int h) {
        ushort_t* As = sbuf + h * HALF;
        ushort_t* Ws = As + MT * 64;
#pragma unroll
        for (int it = 0; it < 4; ++it) {          // W tile 128x64
            int s   = it * 256 + tid;
            int ln  = s & 63;
            int grp = s >> 6;
            int tile = grp >> 1, kst = grp & 1;
            int row = tile * 16 + (ln & 15);
            int kk  = kst * 32 + (ln >> 4) * 8;
            gld_lds16(&W[(size_t)(o0 + row) * K + kc + kk],
                      &Ws[(it * 256 + wave * 64) * 8]);
        }
#pragma unroll
        for (int it = 0; it < MT / 32; ++it) {    // A tile MTx64
            int s   = it * 256 + tid;
            int ln  = s & 63;
            int grp = s >> 6;
            int tile = grp >> 1, kst = grp & 1;
            int row = tile * 16 + (ln & 15);
            int kk  = kst * 32 + (ln >> 4) * 8;
            int ar = gm0 + row; if (ar >= M) ar = M - 1;
            gld_lds16(&A[(size_t)ar * lda + kc + kk],
                      &As[(it * 256 + wave * 64) * 8]);
        }
    };

    floatx4 acc[MI][4];
#pragma unroll
    for (int i = 0; i < MI; ++i)
#pragma unroll
        for (int j = 0; j < 4; ++j) acc[i][j] = (floatx4)(0.f);

    const int nk = K >> 6;
    stage(0, 0);
    __syncthreads();
    for (int t = 0; t < nk; ++t) {
        if (t + 1 < nk) stage((t + 1) * 64, (t + 1) & 1);
        const ushort_t* As = sbuf + (t & 1) * HALF;
        const ushort_t* Ws = As + MT * 64;
#pragma unroll
        for (int kst = 0; kst < 2; ++kst) {
            short8 af[MI], wf[4];
#pragma unroll
            for (int i = 0; i < MI; ++i) {
                int mt = mhalf * MI + i;
                af[i] = *(const short8*)&As[((mt * 2 + kst) * 64 + lane) * 8];
            }
#pragma unroll
            for (int j = 0; j < 4; ++j) {
                int ot = ohalf * 4 + j;
                wf[j] = *(const short8*)&Ws[((ot * 2 + kst) * 64 + lane) * 8];
            }
#pragma unroll
            for (int i = 0; i < MI; ++i)
#pragma unroll
                for (int j = 0; j < 4; ++j)
                    acc[i][j] = __builtin_amdgcn_mfma_f32_16x16x32_bf16(
                        af[i], wf[j], acc[i][j], 0, 0, 0);
        }
        __syncthreads();
    }

    // ---- epilogue ----
    ushort_t* B16 = sbuf;
    float*    B32 = (float*)sbuf;

    if (LN) {
#pragma unroll
        for (int j = 0; j < 4; ++j) {
            int oc = (ohalf * 4 + j) * 16 + (lane & 15);
            float bj = bias[oc];
#pragma unroll
            for (int i = 0; i < MI; ++i) {
                int rbase = gm0 + (mhalf * MI + i) * 16 + (lane >> 4) * 4;
#pragma unroll
                for (int r = 0; r < 4; ++r) {
                    int rowc = rbase + r; if (rowc >= M) rowc = M - 1;
                    float rv = resf ? resf[(size_t)rowc * HID + oc]
                                    : bf2f(resb[(size_t)rowc * HID + oc]);
                    acc[i][j][r] += bj + rv;
                }
            }
        }
#pragma unroll
        for (int i = 0; i < MI; ++i) {
#pragma unroll
            for (int r = 0; r < 4; ++r) {
                float s1 = acc[i][0][r] + acc[i][1][r] + acc[i][2][r] + acc[i][3][r];
                float s2 = acc[i][0][r] * acc[i][0][r] + acc[i][1][r] * acc[i][1][r]
                         + acc[i][2][r] * acc[i][2][r] + acc[i][3][r] * acc[i][3][r];
                s1 += __shfl_xor(s1, 1); s1 += __shfl_xor(s1, 2);
                s1 += __shfl_xor(s1, 4); s1 += __shfl_xor(s1, 8);
                s2 += __shfl_xor(s2, 1); s2 += __shfl_xor(s2, 2);
                s2 += __shfl_xor(s2, 4); s2 += __shfl_xor(s2, 8);
                if ((lane & 15) == 0) {
                    int rl = (mhalf * MI + i) * 16 + (lane >> 4) * 4 + r;
                    pS[rl][ohalf] = s1;
                    pQ[rl][ohalf] = s2;
                }
            }
        }
        __syncthreads();
#pragma unroll
        for (int i = 0; i < MI; ++i) {
#pragma unroll
            for (int r = 0; r < 4; ++r) {
                int rl = (mhalf * MI + i) * 16 + (lane >> 4) * 4 + r;
                float S = pS[rl][0] + pS[rl][1];
                float Q = pQ[rl][0] + pQ[rl][1];
                float mu = S * (1.f / 128.f);
                float var = Q * (1.f / 128.f) - mu * mu;
                float rstd = rsqrtf(var + 1e-5f);
#pragma unroll
                for (int j = 0; j < 4; ++j) {
                    int oc = (ohalf * 4 + j) * 16 + (lane & 15);
                    acc[i][j][r] = (acc[i][j][r] - mu) * rstd * g[oc] + be[oc];
                }
            }
        }
        __syncthreads();
    }

    if (OUTF == 0 || (OUTF == 3 && blockIdx.y == 0)) {
#pragma unroll
        for (int i = 0; i < MI; ++i)
#pragma unroll
            for (int j = 0; j < 4; ++j) {
                int oc = (ohalf * 4 + j) * 16 + (lane & 15);
                float bj = LN ? 0.f : bias[o0 + oc];
#pragma unroll
                for (int r = 0; r < 4; ++r) {
                    int rl = (mhalf * MI + i) * 16 + (lane >> 4) * 4 + r;
                    float v = acc[i][j][r] + bj;
                    if (ACT) v = gelu_f(v);
                    B16[rl * 136 + oc] = f2bf(v);
                }
            }
        __syncthreads();
        const int oo = (OUTF == 3) ? 0 : o0;
#pragma unroll
        for (int p = 0; p < MT / 16; ++p) {
            int row = p * 16 + (tid >> 4);
            int ch  = tid & 15;
            if (gm0 + row < M)
                *(short8*)&outb[(size_t)(gm0 + row) * ostride + oo + ch * 8] =
                    *(const short8*)&B16[row * 136 + ch * 8];
        }
    } else if (OUTF == 2 || OUTF == 3) {
        // fp8 e4m3 out with x64 scale, into interleaved kv chunks of 512B row
#pragma unroll
        for (int i = 0; i < MI; ++i)
#pragma unroll
            for (int j = 0; j < 4; ++j) {
                int oc = (ohalf * 4 + j) * 16 + (lane & 15);
                float bj = bias[o0 + oc];
#pragma unroll
                for (int r = 0; r < 4; ++r) {
                    int rl = (mhalf * MI + i) * 16 + (lane >> 4) * 4 + r;
                    float v = (acc[i][j][r] + bj) * KV_SCALE;
                    B16[rl * 136 + oc] = f2bf(v);
                }
            }
        __syncthreads();
        const int koff = (OUTF == 3) ? (blockIdx.y - 1) * 8 : blockIdx.y * 8;
#pragma unroll
        for (int p = 0; p < MT / 16; ++p) {
            int row = p * 16 + (tid >> 4);
            int ch  = tid & 15;
            if (gm0 + row < M) {
                short8 s = *(const short8*)&B16[row * 136 + ch * 8];
                unsigned u0 = 0, u1 = 0;
                u0 = __builtin_amdgcn_cvt_pk_fp8_f32(
                         bf2f((ushort_t)s[0]), bf2f((ushort_t)s[1]), u0, false);
                u0 = __builtin_amdgcn_cvt_pk_fp8_f32(
                         bf2f((ushort_t)s[2]), bf2f((ushort_t)s[3]), u0, true);
                u1 = __builtin_amdgcn_cvt_pk_fp8_f32(
                         bf2f((ushort_t)s[4]), bf2f((ushort_t)s[5]), u1, false);
                u1 = __builtin_amdgcn_cvt_pk_fp8_f32(
                         bf2f((ushort_t)s[6]), bf2f((ushort_t)s[7]), u1, true);
                uint2 o; o.x = u0; o.y = u1;
                *(uint2*)((char*)outb + (size_t)(gm0 + row) * QKV_ROWB
                          + 256 + ch * 16 + koff) = o;
            }
        }
    } else {
#pragma unroll
        for (int p = 0; p < 2; ++p) {
            if (ohalf == p) {
#pragma unroll
                for (int i = 0; i < MI; ++i)
#pragma unroll
                    for (int j = 0; j < 4; ++j) {
                        int ocl = j * 16 + (lane & 15);
                        float bj = LN ? 0.f : bias[p * 64 + ocl];
#pragma unroll
                        for (int r = 0; r < 4; ++r) {
                            int rl = (mhalf * MI + i) * 16 + (lane >> 4) * 4 + r;
                            float v = acc[i][j][r] + bj;
                            if (ACT) v = gelu_f(v);
                            B32[rl * 68 + ocl] = v;
                        }
                    }
            }
            __syncthreads();
#pragma unroll
            for (int q = 0; q < MT / 16; ++q) {
                int row = q * 16 + (tid >> 4);
                int ch  = tid & 15;
                if (gm0 + row < M)
                    *(float4*)&outf[(size_t)(gm0 + row) * ostride + o0 + p * 64 + ch * 4] =
                        *(const float4*)&B32[row * 68 + ch * 4];
            }
            __syncthreads();
        }
    }
}

// ---------------- fused FF1+GELU+FF2+LN2 kernel ------------------------------
// 16 W-panels (4 ff-chunks x {W1 kc0, W1 kc1, W2 kc0, W2 kc1}), double-buffered:
// panel p+1's global_load_lds issued before MFMA(panel p); ONE barrier/phase.
// a1 tile: unpadded [64][128] ushort with XOR swizzle byte^=((row&7)<<4)
// (m214-style fix for 256B-row ds_read_b128 bank conflicts).
__global__ __launch_bounds__(256)
void ff_fused_kernel(const ushort_t* __restrict__ hb,   // [M][128] bf16
                     const ushort_t* __restrict__ w1,   // [512][128] bf16
                     const float* __restrict__ b1,
                     const ushort_t* __restrict__ w2,   // [128][512] bf16
                     const float* __restrict__ b2,
                     const float* __restrict__ g, const float* __restrict__ be,
                     float* __restrict__ out, int M)
{
    __shared__ __align__(16) ushort_t Hs[8192];    // h tile, permuted A layout
    __shared__ __align__(16) ushort_t wst[16384];  // 2 x 128x64 W panel (dbuf)
    __shared__ __align__(16) ushort_t a1t[8192];   // [64][128] swizzled
    __shared__ float pS[64][2];
    __shared__ float pQ[64][2];

    const int tid = threadIdx.x;
    const int wave = tid >> 6, lane = tid & 63;
    const int gm0 = blockIdx.x * 64;
    const int mhalf = wave >> 1, ohalf = wave & 1;

    auto stage_panel = [&](int p, int h) {
        int c = p >> 2, sub = p & 3;
        ushort_t* dst = wst + h * 8192;
#pragma unroll
        for (int it = 0; it < 4; ++it) {
            int s = it * 256 + tid;
            int l = s & 63;
            int grp = s >> 6;
            int tile = grp >> 1, kst = grp & 1;
            int row = tile * 16 + (l & 15);
            int kk = kst * 32 + (l >> 4) * 8;
            const ushort_t* src;
            if (sub < 2) src = &w1[(size_t)(c * 128 + row) * HID + sub * 64 + kk];
            else         src = &w2[(size_t)row * 512 + c * 128 + (sub - 2) * 64 + kk];
            gld_lds16(src, &dst[(it * 256 + wave * 64) * 8]);
        }
    };

    // ---- prologue: stage h tile (permuted A layout) + panel 0 ----
#pragma unroll
    for (int it = 0; it < 4; ++it) {
        int s = it * 256 + tid;
        int l = s & 63;
        int g8 = (s >> 6) & 7;          // grp within k-panel (tile*2+kst)
        int kc = s >> 9;                // k-panel (64 each)
        int tile = g8 >> 1, kst = g8 & 1;
        int row = tile * 16 + (l & 15);
        int kk = kc * 64 + kst * 32 + (l >> 4) * 8;
        int ar = gm0 + row; if (ar >= M) ar = M - 1;
        gld_lds16(&hb[(size_t)ar * HID + kk], &Hs[(it * 256 + wave * 64) * 8]);
    }
    stage_panel(0, 0);
    __syncthreads();

    floatx4 acc2[2][4];
#pragma unroll
    for (int i = 0; i < 2; ++i)
#pragma unroll
        for (int j = 0; j < 4; ++j) acc2[i][j] = (floatx4)(0.f);

    floatx4 acc1[2][4];

    for (int p = 0; p < 16; ++p) {
        const int sub = p & 3;
        const int c   = p >> 2;
        if (p + 1 < 16) stage_panel(p + 1, (p + 1) & 1);
        const ushort_t* wbuf = wst + (p & 1) * 8192;

        if (sub == 0) {
#pragma unroll
            for (int i = 0; i < 2; ++i)
#pragma unroll
                for (int j = 0; j < 4; ++j) acc1[i][j] = (floatx4)(0.f);
        }

        if (sub < 2) {
            // ---- GEMM1 K-panel sub: h @ W1chunk^T ----
#pragma unroll
            for (int kst = 0; kst < 2; ++kst) {
                short8 af[2], wf[4];
#pragma unroll
                for (int i = 0; i < 2; ++i) {
                    int mt = mhalf * 2 + i;
                    af[i] = *(const short8*)&Hs[(((sub << 3) + mt * 2 + kst) * 64 + lane) * 8];
                }
#pragma unroll
                for (int j = 0; j < 4; ++j) {
                    int ot = ohalf * 4 + j;
                    wf[j] = *(const short8*)&wbuf[((ot * 2 + kst) * 64 + lane) * 8];
                }
#pragma unroll
                for (int i = 0; i < 2; ++i)
#pragma unroll
                    for (int j = 0; j < 4; ++j)
                        acc1[i][j] = __builtin_amdgcn_mfma_f32_16x16x32_bf16(
                            af[i], wf[j], acc1[i][j], 0, 0, 0);
            }
            if (sub == 1) {
                // ---- GELU -> a1 tile (swizzled write) ----
#pragma unroll
                for (int i = 0; i < 2; ++i)
#pragma unroll
                    for (int j = 0; j < 4; ++j) {
                        int oc = (ohalf * 4 + j) * 16 + (lane & 15);
                        float bj = b1[c * 128 + oc];
#pragma unroll
                        for (int r = 0; r < 4; ++r) {
                            int rl = (mhalf * 2 + i) * 16 + (lane >> 4) * 4 + r;
                            *(ushort_t*)((char*)a1t + rl * 256 +
                                         ((oc * 2) ^ ((rl & 7) << 4))) =
                                f2bf(gelu_f(acc1[i][j][r] + bj));
                        }
                    }
            }
        } else {
            // ---- GEMM2 partial: a1 @ W2[:, c*128 + kc2*64 ..]^T ----
            const int kc2 = sub - 2;
#pragma unroll
            for (int kst = 0; kst < 2; ++kst) {
                short8 af[2], wf[4];
#pragma unroll
                for (int i = 0; i < 2; ++i) {
                    int ar = (mhalf * 2 + i) * 16 + (lane & 15);
                    int bc = kc2 * 128 + kst * 64 + (lane >> 4) * 16;
                    af[i] = *(const short8*)((const char*)a1t + ar * 256 +
                                             (bc ^ ((ar & 7) << 4)));
                }
#pragma unroll
                for (int j = 0; j < 4; ++j) {
                    int ot = ohalf * 4 + j;
                    wf[j] = *(const short8*)&wbuf[((ot * 2 + kst) * 64 + lane) * 8];
                }
#pragma unroll
                for (int i = 0; i < 2; ++i)
#pragma unroll
                    for (int j = 0; j < 4; ++j)
                        acc2[i][j] = __builtin_amdgcn_mfma_f32_16x16x32_bf16(
                            af[i], wf[j], acc2[i][j], 0, 0, 0);
            }
        }
        __syncthreads();
    }

    // ---- LN2 epilogue: bias + residual (from resident Hs tile) ----
#pragma unroll
    for (int j = 0; j < 4; ++j) {
        int oc = (ohalf * 4 + j) * 16 + (lane & 15);
        float bj = b2[oc];
#pragma unroll
        for (int i = 0; i < 2; ++i) {
#pragma unroll
            for (int r = 0; r < 4; ++r) {
                int rl = (mhalf * 2 + i) * 16 + (lane >> 4) * 4 + r;
                float rv = bf2f(Hs[(((oc >> 6) * 8 + (rl >> 4) * 2 + ((oc >> 5) & 1)) * 64
                                    + (rl & 15) + ((oc >> 3) & 3) * 16) * 8 + (oc & 7)]);
                acc2[i][j][r] += bj + rv;
            }
        }
    }
#pragma unroll
    for (int i = 0; i < 2; ++i) {
#pragma unroll
        for (int r = 0; r < 4; ++r) {
            float s1 = acc2[i][0][r] + acc2[i][1][r] + acc2[i][2][r] + acc2[i][3][r];
            float s2 = acc2[i][0][r] * acc2[i][0][r] + acc2[i][1][r] * acc2[i][1][r]
                     + acc2[i][2][r] * acc2[i][2][r] + acc2[i][3][r] * acc2[i][3][r];
            s1 += __shfl_xor(s1, 1); s1 += __shfl_xor(s1, 2);
            s1 += __shfl_xor(s1, 4); s1 += __shfl_xor(s1, 8);
            s2 += __shfl_xor(s2, 1); s2 += __shfl_xor(s2, 2);
            s2 += __shfl_xor(s2, 4); s2 += __shfl_xor(s2, 8);
            if ((lane & 15) == 0) {
                int rl = (mhalf * 2 + i) * 16 + (lane >> 4) * 4 + r;
                pS[rl][ohalf] = s1;
                pQ[rl][ohalf] = s2;
            }
        }
    }
    __syncthreads();
#pragma unroll
    for (int i = 0; i < 2; ++i) {
#pragma unroll
        for (int r = 0; r < 4; ++r) {
            int rl = (mhalf * 2 + i) * 16 + (lane >> 4) * 4 + r;
            float S = pS[rl][0] + pS[rl][1];
            float Q = pQ[rl][0] + pQ[rl][1];
            float mu = S * (1.f / 128.f);
            float var = Q * (1.f / 128.f) - mu * mu;
            float rstd = rsqrtf(var + 1e-5f);
#pragma unroll
            for (int j = 0; j < 4; ++j) {
                int oc = (ohalf * 4 + j) * 16 + (lane & 15);
                acc2[i][j][r] = (acc2[i][j][r] - mu) * rstd * g[oc] + be[oc];
            }
        }
    }
    __syncthreads();

    // ---- f32 store via two-pass LDS staging (reuse wst) ----
    float* B32 = (float*)wst;
#pragma unroll
    for (int p = 0; p < 2; ++p) {
        if (ohalf == p) {
#pragma unroll
            for (int i = 0; i < 2; ++i)
#pragma unroll
                for (int j = 0; j < 4; ++j) {
                    int ocl = j * 16 + (lane & 15);
#pragma unroll
                    for (int r = 0; r < 4; ++r) {
                        int rl = (mhalf * 2 + i) * 16 + (lane >> 4) * 4 + r;
                        B32[rl * 68 + ocl] = acc2[i][j][r];
                    }
                }
        }
        __syncthreads();
#pragma unroll
        for (int q = 0; q < 4; ++q) {
            int row = q * 16 + (tid >> 4);
            int ch  = tid & 15;
            if (gm0 + row < M)
                *(float4*)&out[(size_t)(gm0 + row) * HID + p * 64 + ch * 4] =
                    *(const float4*)&B32[row * 68 + ch * 4];
        }
        __syncthreads();
    }
}

// ---------------- counting-sort scan chain ----------------------------------
__global__ __launch_bounds__(256)
void scan1_kernel(const int* __restrict__ cnt, int* __restrict__ parts, int N)
{
    __shared__ int sd[256];
    int t = threadIdx.x;
    int base = blockIdx.x * 1024 + t * 4;
    int s = 0;
#pragma unroll
    for (int j = 0; j < 4; ++j) if (base + j < N) s += cnt[base + j];
    sd[t] = s; __syncthreads();
    for (int off = 128; off; off >>= 1) {
        if (t < off) sd[t] += sd[t + off];
        __syncthreads();
    }
    if (t == 0) parts[blockIdx.x] = sd[0];
}

__global__ __launch_bounds__(256)
void scan2_kernel(const int* __restrict__ parts, int* __restrict__ poff, int nb)
{
    __shared__ int sd[256];
    int t = threadIdx.x;
    int v = (t < nb) ? parts[t] : 0;
    sd[t] = v; __syncthreads();
    for (int off = 1; off < 256; off <<= 1) {
        int u = (t >= off) ? sd[t - off] : 0;
        __syncthreads();
        sd[t] += u;
        __syncthreads();
    }
    if (t < nb) poff[t] = sd[t] - v;   // exclusive
}

__global__ __launch_bounds__(256)
void scan3_kernel(const int* __restrict__ cnt, const int* __restrict__ poff,
                  int* __restrict__ rp, int N)
{
    __shared__ int sd[256];
    int t = threadIdx.x;
    int base = blockIdx.x * 1024 + t * 4;
    int v0 = (base + 0 < N) ? cnt[base + 0] : 0;
    int v1 = (base + 1 < N) ? cnt[base + 1] : 0;
    int v2 = (base + 2 < N) ? cnt[base + 2] : 0;
    int v3 = (base + 3 < N) ? cnt[base + 3] : 0;
    int s = v0 + v1 + v2 + v3;
    sd[t] = s; __syncthreads();
    for (int off = 1; off < 256; off <<= 1) {
        int u = (t >= off) ? sd[t - off] : 0;
        __syncthreads();
        sd[t] += u;
        __syncthreads();
    }
    int o = poff[blockIdx.x] + sd[t] - s;
    if (base + 0 < N) rp[base + 0] = o;
    if (base + 1 < N) rp[base + 1] = o + v0;
    if (base + 2 < N) rp[base + 2] = o + v0 + v1;
    if (base + 3 < N) rp[base + 3] = o + v0 + v1 + v2;
}

// cohort scatter: blockIdx.x & 7 keys the XCD (round-robin dispatch heuristic);
// cohort r scatters only dst in its 1/8 node range -> each XCD's active write
// window is ~400KB and 64B lines are shared within ONE L2 only.
__global__ __launch_bounds__(256)
void scatter_kernel(const int* __restrict__ src, const int* __restrict__ dst,
                    int* __restrict__ rp, int* __restrict__ ssrc, int E, int N)
{
    int coh = blockIdx.x & 7;
    int bc  = blockIdx.x >> 3;
    int rr  = (N + 7) >> 3;
    int nlo = coh * rr;
    int nhi = nlo + rr; if (nhi > N) nhi = N;
    int stride = (gridDim.x >> 3) * 256;
    for (int e = bc * 256 + threadIdx.x; e < E; e += stride) {
        int d = dst[e];
        if (d >= nlo && d < nhi) {
            int pos = atomicAdd(&rp[d], 1);
            ssrc[pos] = src[e];
        }
    }
}

// ---------------- fused attention: 4 edges per wave-step ---------------------
__global__ __launch_bounds__(256)
void attn_fused_kernel(const ushort_t* __restrict__ qkvb, const int* __restrict__ rp,
                       const int* __restrict__ ssrc, ushort_t* __restrict__ aggb, int N)
{
    int wave = threadIdx.x >> 6, lane = threadIdx.x & 63;
    int n = blockIdx.x * 4 + wave;
    if (n >= N) return;
    int grp = lane >> 4;            // 0..3 edge slot
    int cb  = (lane & 15) * 16;     // byte offset of this lane's 16B chunk
    const char* base = (const char*)qkvb;

    short8 qv = *(const short8*)(base + n * QKV_ROWB + cb);
    float q[8];
#pragma unroll
    for (int j = 0; j < 8; ++j) q[j] = bf2f((ushort_t)qv[j]) * (0.25f / KV_SCALE);

    int r0 = n ? rp[n - 1] : 0;
    int r1 = rp[n];
    float acc[8] = {0.f, 0.f, 0.f, 0.f, 0.f, 0.f, 0.f, 0.f};
    float l = 0.f;

    int r = r0;
    for (; r + 8 <= r1; r += 8) {            // two full 4-edge steps
        int s0 = ssrc[r + grp];
        int s1 = ssrc[r + 4 + grp];
        uint4 kv0 = *(const uint4*)(base + s0 * QKV_ROWB + 256 + cb);
        uint4 kv1 = *(const uint4*)(base + s1 * QKV_ROWB + 256 + cb);

        f32x2 a0 = __builtin_amdgcn_cvt_pk_f32_fp8(kv0.x, false);
        f32x2 a1 = __builtin_amdgcn_cvt_pk_f32_fp8(kv0.x, true);
        f32x2 a2 = __builtin_amdgcn_cvt_pk_f32_fp8(kv0.y, false);
        f32x2 a3 = __builtin_amdgcn_cvt_pk_f32_fp8(kv0.y, true);
        f32x2 b0 = __builtin_amdgcn_cvt_pk_f32_fp8(kv1.x, false);
        f32x2 b1 = __builtin_amdgcn_cvt_pk_f32_fp8(kv1.x, true);
        f32x2 b2 = __builtin_amdgcn_cvt_pk_f32_fp8(kv1.y, false);
        f32x2 b3 = __builtin_amdgcn_cvt_pk_f32_fp8(kv1.y, true);

        float p0 = 0.f, p1 = 0.f;
        p0 = fmaf(q[0], a0.x, p0); p0 = fmaf(q[1], a0.y, p0);
        p0 = fmaf(q[2], a1.x, p0); p0 = fmaf(q[3], a1.y, p0);
        p0 = fmaf(q[4], a2.x, p0); p0 = fmaf(q[5], a2.y, p0);
        p0 = fmaf(q[6], a3.x, p0); p0 = fmaf(q[7], a3.y, p0);
        p1 = fmaf(q[0], b0.x, p1); p1 = fmaf(q[1], b0.y, p1);
        p1 = fmaf(q[2], b1.x, p1); p1 = fmaf(q[3], b1.y, p1);
        p1 = fmaf(q[4], b2.x, p1); p1 = fmaf(q[5], b2.y, p1);
        p1 = fmaf(q[6], b3.x, p1); p1 = fmaf(q[7], b3.y, p1);

        p0 += __shfl_xor(p0, 1);             // per-head dot (head = 2 lanes)
        p1 += __shfl_xor(p1, 1);
        float e0 = __expf(p0), e1 = __expf(p1);
        l += e0 + e1;

        f32x2 v0 = __builtin_amdgcn_cvt_pk_f32_fp8(kv0.z, false);
        f32x2 v1 = __builtin_amdgcn_cvt_pk_f32_fp8(kv0.z, true);
        f32x2 v2 = __builtin_amdgcn_cvt_pk_f32_fp8(kv0.w, false);
        f32x2 v3 = __builtin_amdgcn_cvt_pk_f32_fp8(kv0.w, true);
        f32x2 w0 = __builtin_amdgcn_cvt_pk_f32_fp8(kv1.z, false);
        f32x2 w1 = __builtin_amdgcn_cvt_pk_f32_fp8(kv1.z, true);
        f32x2 w2 = __builtin_amdgcn_cvt_pk_f32_fp8(kv1.w, false);
        f32x2 w3 = __builtin_amdgcn_cvt_pk_f32_fp8(kv1.w, true);

        acc[0] = fmaf(e0, v0.x, acc[0]); acc[1] = fmaf(e0, v0.y, acc[1]);
        acc[2] = fmaf(e0, v1.x, acc[2]); acc[3] = fmaf(e0, v1.y, acc[3]);
        acc[4] = fmaf(e0, v2.x, acc[4]); acc[5] = fmaf(e0, v2.y, acc[5]);
        acc[6] = fmaf(e0, v3.x, acc[6]); acc[7] = fmaf(e0, v3.y, acc[7]);
        acc[0] = fmaf(e1, w0.x, acc[0]); acc[1] = fmaf(e1, w0.y, acc[1]);
        acc[2] = fmaf(e1, w1.x, acc[2]); acc[3] = fmaf(e1, w1.y, acc[3]);
        acc[4] = fmaf(e1, w2.x, acc[4]); acc[5] = fmaf(e1, w2.y, acc[5]);
        acc[6] = fmaf(e1, w3.x, acc[6]); acc[7] = fmaf(e1, w3.y, acc[7]);
    }
    for (; r < r1; r += 4) {                 // masked tail (<= 2 steps)
        int e = r + grp;
        int s = ssrc[(e < r1) ? e : r0];
        uint4 kv = *(const uint4*)(base + s * QKV_ROWB + 256 + cb);
        f32x2 a0 = __builtin_amdgcn_cvt_pk_f32_fp8(kv.x, false);
        f32x2 a1 = __builtin_amdgcn_cvt_pk_f32_fp8(kv.x, true);
        f32x2 a2 = __builtin_amdgcn_cvt_pk_f32_fp8(kv.y, false);
        f32x2 a3 = __builtin_amdgcn_cvt_pk_f32_fp8(kv.y, true);
        float p = 0.f;
        p = fmaf(q[0], a0.x, p); p = fmaf(q[1], a0.y, p);
        p = fmaf(q[2], a1.x, p); p = fmaf(q[3], a1.y, p);
        p = fmaf(q[4], a2.x, p); p = fmaf(q[5], a2.y, p);
        p = fmaf(q[6], a3.x, p); p = fmaf(q[7], a3.y, p);
        p += __shfl_xor(p, 1);
        float ea = (e < r1) ? __expf(p) : 0.f;
        l += ea;
        f32x2 v0 = __builtin_amdgcn_cvt_pk_f32_fp8(kv.z, false);
        f32x2 v1 = __builtin_amdgcn_cvt_pk_f32_fp8(kv.z, true);
        f32x2 v2 = __builtin_amdgcn_cvt_pk_f32_fp8(kv.w, false);
        f32x2 v3 = __builtin_amdgcn_cvt_pk_f32_fp8(kv.w, true);
        acc[0] = fmaf(ea, v0.x, acc[0]); acc[1] = fmaf(ea, v0.y, acc[1]);
        acc[2] = fmaf(ea, v1.x, acc[2]); acc[3] = fmaf(ea, v1.y, acc[3]);
        acc[4] = fmaf(ea, v2.x, acc[4]); acc[5] = fmaf(ea, v2.y, acc[5]);
        acc[6] = fmaf(ea, v3.x, acc[6]); acc[7] = fmaf(ea, v3.y, acc[7]);
    }

    // merge the 4 edge-group partial sums (channels match across xor16/32)
#pragma unroll
    for (int j = 0; j < 8; ++j) {
        acc[j] += __shfl_xor(acc[j], 16);
        acc[j] += __shfl_xor(acc[j], 32);
    }
    l += __shfl_xor(l, 16);
    l += __shfl_xor(l, 32);
    float inv = KV_INV_SCALE / (l + 1e-16f);   // folds the /64 v-scale
    if (grp == 0) {
        short8 o;
#pragma unroll
        for (int j = 0; j < 8; ++j) o[j] = (short)f2bf(acc[j] * inv);
        *(short8*)((char*)aggb + n * 256 + cb) = o;
    }
}

// ============================================================================
extern "C" void kernel_launch(void* const* d_in, const int* in_sizes, int n_in,
                              void* d_out, int out_size, void* d_ws, size_t ws_size,
                              hipStream_t stream)
{
    const float* x  = (const float*)d_in[0];
    const int*   ei = (const int*)d_in[1];
    const float* Wq = (const float*)d_in[2];
    const float* bq = (const float*)d_in[3];
    const float* Wk = (const float*)d_in[4];
    const float* bk = (const float*)d_in[5];
    const float* Wv = (const float*)d_in[6];
    const float* bv = (const float*)d_in[7];
    const float* Wo = (const float*)d_in[8];
    const float* bo = (const float*)d_in[9];
    const float* W1 = (const float*)d_in[10];
    const float* b1 = (const float*)d_in[11];
    const float* W2 = (const float*)d_in[12];
    const float* b2 = (const float*)d_in[13];
    const float* g1 = (const float*)d_in[14];
    const float* be1= (const float*)d_in[15];
    const float* g2 = (const float*)d_in[16];
    const float* be2= (const float*)d_in[17];
    float* out = (float*)d_out;

    const int N = in_sizes[0] / HID;      // 50000
    const int E = in_sizes[1] / 2;        // 800000
    const int* srcp = ei;
    const int* dstp = ei + E;

    const size_t NH = (size_t)N * HID;    // 6.4M
    float* wsf = (float*)d_ws;

    // ---- workspace layout (f32 units) ----
    ushort_t* xb   = (ushort_t*)wsf;                  // [0, 0.5NH)  dies after QKV
    ushort_t* qkvb = (ushort_t*)(wsf + NH / 2);       // [0.5, 1.5)  512B/row, dies after attn
    ushort_t* aggb = (ushort_t*)(wsf + 2 * NH);       // [2.0, 2.5)  dies after Wo
    ushort_t* hb   = (ushort_t*)wsf;                  // [0, 0.5)    overlays dead xb

    ushort_t* wts  = (ushort_t*)(wsf + 2 * NH + NH / 2);  // 196608 ushort
    float*    bqkv = (float*)(wts + 196608);              // 384 f32
    int*      rp   = (int*)(bqkv + 384);                  // N+1
    int*      cnt  = rp + (N + 1);                        // N
    int*      poff = cnt + N;                             // 256
    int*      parts= poff + 256;                          // 256
    int*      ssrc = parts + 256;                         // E

    // ---- prep (+fused degree count; cnt zeroed first) ----
    hipMemsetAsync(cnt, 0, N * sizeof(int), stream);
    const int xpairs = (int)(NH / 2);
    const int ptot   = xpairs + 98304 + 384 + E;
    prep_kernel<<<(ptot + 255) / 256, 256, 0, stream>>>(
        x, Wq, Wk, Wv, Wo, W1, W2, bq, bk, bv, dstp, cnt, E,
        xb, wts, bqkv, xpairs);

    // ---- counting sort of edges by dst ----
    const int nb = (N + 1023) / 1024;   // 49
    scan1_kernel<<<nb, 256, 0, stream>>>(cnt, parts, N);
    scan2_kernel<<<1, 256, 0, stream>>>(parts, poff, nb);
    scan3_kernel<<<nb, 256, 0, stream>>>(cnt, poff, rp, N);
    scatter_kernel<<<2048, 256, 0, stream>>>(srcp, dstp, rp, ssrc, E, N);

    const int gx64 = (N + 63) / 64;     // 782

    // ---- merged QKV: y=0 -> q bf16, y=1/2 -> k/v fp8 ----
    gemm_t<64, 0, 0, 3><<<dim3(gx64, 3), 256, 0, stream>>>(
        xb, HID, N, wts, HID, bqkv, nullptr, qkvb, 256,
        nullptr, nullptr, nullptr, nullptr);

    // ---- fused attention ----
    attn_fused_kernel<<<(N + 3) / 4, 256, 0, stream>>>(qkvb, rp, ssrc, aggb, N);

    // ---- Wo + fused residual(x) + LN1 -> hb (bf16) ----
    gemm_t<64, 0, 1, 0><<<dim3(gx64, 1), 256, 0, stream>>>(
        aggb, HID, N, wts + 49152, HID, bo, nullptr, hb, HID,
        x, nullptr, g1, be1);

    // ---- fused FF1 + GELU + FF2 + residual(hb) + LN2 -> out (f32) ----
    ff_fused_kernel<<<gx64, 256, 0, stream>>>(
        hb, wts + 65536, b1, wts + 131072, b2, g2, be2, out, N);
}

// Round 5
// 331.900 us; speedup vs baseline: 1.0190x; 1.0190x over previous
//
#include <hip/hip_runtime.h>
#include <math.h>

#define N_HEADS 8
#define HEAD_DIM 16
#define HID 128
// qkv row: 256B q (bf16) + 16 x [8B k fp8 | 8B v fp8] = 512B
#define QKV_ROWB 512

typedef unsigned short ushort_t;
typedef __attribute__((ext_vector_type(8))) short short8;
typedef __attribute__((ext_vector_type(4))) float floatx4;
typedef __attribute__((ext_vector_type(2))) float f32x2;

#define KV_SCALE 64.0f
#define KV_INV_SCALE 0.015625f

// FF fp8 scales: W1,W2 x 2^16; a1 x 2^13; h x 1
#define W_SCALE 65536.0f
#define A1_SCALE 8192.0f
#define G1_DESCALE (1.0f / 65536.0f)
#define G2_DESCALE (1.0f / 536870912.0f)   // 1/(8192*65536)

// byte-offset XOR swizzle for row-major fp8 LDS tiles (8B read granules)
#define FF_SWZ(r, p) ((p) ^ (((r) & 7) << 3))

__device__ __forceinline__ ushort_t f2bf(float f) {
    unsigned u = __float_as_uint(f);
    unsigned r = (u + 0x7FFFu + ((u >> 16) & 1u)) >> 16;
    return (ushort_t)r;
}
__device__ __forceinline__ float bf2f(ushort_t u) {
    return __uint_as_float(((unsigned)u) << 16);
}

__device__ __forceinline__ void gld_lds16(const void* g, void* l) {
    __builtin_amdgcn_global_load_lds(
        (const __attribute__((address_space(1))) void*)g,
        (__attribute__((address_space(3))) void*)l, 16, 0, 0);
}

// fast exact-GELU: erf via Abramowitz-Stegun 7.1.26 (|err| <= 1.5e-7)
__device__ __forceinline__ float gelu_f(float x) {
    float z = fabsf(x) * 0.70710678118654752f;
    float t = 1.0f / (1.0f + 0.3275911f * z);
    float y = t * (0.254829592f + t * (-0.284496736f + t * (1.421413741f
            + t * (-1.453152027f + t * 1.061405429f))));
    float e = 1.0f - y * __expf(-z * z);
    e = copysignf(e, x);
    return 0.5f * x * (1.0f + e);
}

// ---- prep: cvt x, cvt Wq..Wo bf16, pack qkv bias, fp8 W1/W2 images, degrees --
__global__ __launch_bounds__(256)
void prep_kernel(const float* __restrict__ x,
                 const float* __restrict__ Wq, const float* __restrict__ Wk,
                 const float* __restrict__ Wv, const float* __restrict__ Wo,
                 const float* __restrict__ W1, const float* __restrict__ W2,
                 const float* __restrict__ bq, const float* __restrict__ bk,
                 const float* __restrict__ bv,
                 const int* __restrict__ dst, int* __restrict__ cnt, int E,
                 ushort_t* __restrict__ xb, ushort_t* __restrict__ wts,
                 float* __restrict__ bqkv,
                 unsigned char* __restrict__ w1f8,
                 unsigned char* __restrict__ w2f8, int xpairs)
{
    int i = blockIdx.x * 256 + threadIdx.x;
    if (i < xpairs) {
        float2 v = ((const float2*)x)[i];
        xb[i * 2]     = f2bf(v.x);
        xb[i * 2 + 1] = f2bf(v.y);
        return;
    }
    int j = i - xpairs;
    if (j < 32768) {                        // Wq,Wk,Wv,Wo -> bf16
        const float* s; int off;
        if (j < 8192)       { s = Wq; off = j; }
        else if (j < 16384) { s = Wk; off = j - 8192; }
        else if (j < 24576) { s = Wv; off = j - 16384; }
        else                { s = Wo; off = j - 24576; }
        float2 v = ((const float2*)s)[off];
        wts[j * 2]     = f2bf(v.x);
        wts[j * 2 + 1] = f2bf(v.y);
        return;
    }
    int b = j - 32768;
    if (b < 384) {
        bqkv[b] = (b < 128) ? bq[b] : (b < 256) ? bk[b - 128] : bv[b - 256];
        return;
    }
    int c = b - 384;
    if (c < 8192) {                         // w1f8 [512][128], pre-swizzled
        int row = c >> 4, p8 = (c & 15) * 8;
        const float* s = W1 + (size_t)row * HID + (p8 ^ ((row & 7) << 3));
        unsigned u0 = 0, u1 = 0;
        u0 = __builtin_amdgcn_cvt_pk_fp8_f32(s[0]*W_SCALE, s[1]*W_SCALE, u0, false);
        u0 = __builtin_amdgcn_cvt_pk_fp8_f32(s[2]*W_SCALE, s[3]*W_SCALE, u0, true);
        u1 = __builtin_amdgcn_cvt_pk_fp8_f32(s[4]*W_SCALE, s[5]*W_SCALE, u1, false);
        u1 = __builtin_amdgcn_cvt_pk_fp8_f32(s[6]*W_SCALE, s[7]*W_SCALE, u1, true);
        uint2 o; o.x = u0; o.y = u1;
        *(uint2*)&w1f8[(size_t)row * 128 + p8] = o;
        return;
    }
    int c2 = c - 8192;
    if (c2 < 8192) {                        // w2f8 [128][512], pre-swizzled
        int row = c2 >> 6, p8 = (c2 & 63) * 8;
        const float* s = W2 + (size_t)row * 512 + (p8 ^ ((row & 7) << 3));
        unsigned u0 = 0, u1 = 0;
        u0 = __builtin_amdgcn_cvt_pk_fp8_f32(s[0]*W_SCALE, s[1]*W_SCALE, u0, false);
        u0 = __builtin_amdgcn_cvt_pk_fp8_f32(s[2]*W_SCALE, s[3]*W_SCALE, u0, true);
        u1 = __builtin_amdgcn_cvt_pk_fp8_f32(s[4]*W_SCALE, s[5]*W_SCALE, u1, false);
        u1 = __builtin_amdgcn_cvt_pk_fp8_f32(s[6]*W_SCALE, s[7]*W_SCALE, u1, true);
        uint2 o; o.x = u0; o.y = u1;
        *(uint2*)&w2f8[(size_t)row * 512 + p8] = o;
        return;
    }
    int e = c2 - 8192;
    if (e < E) atomicAdd(&cnt[dst[e]], 1);
}

// ---------------- templated bf16 MFMA GEMM (MT=64) --------------------------
// Double-buffered K-panels. OUTF: 0 = bf16 out (+optional fp8 h image via outf
// when LN), 1 = f32 out, 3 = merged QKV (y=0 q bf16, y=1/2 k/v fp8).
template<int MT, int ACT, int LN, int OUTF>
__global__ __launch_bounds__(256)
void gemm_t(const ushort_t* __restrict__ A, int lda, int M,
            const ushort_t* __restrict__ W, int K,
            const float* __restrict__ bias,
            float* __restrict__ outf, ushort_t* __restrict__ outb, int ostride,
            const float* __restrict__ resf, const ushort_t* __restrict__ resb,
            const float* __restrict__ g, const float* __restrict__ be)
{
    constexpr int MI   = MT / 32;
    constexpr int HALF = MT * 64 + 128 * 64;
    constexpr int BNC  = MT * 136;
    constexpr int SB   = (2 * HALF > BNC) ? 2 * HALF : BNC;
    __shared__ __align__(16) ushort_t sbuf[SB];
    __shared__ float pS[LN ? MT : 1][2];
    __shared__ float pQ[LN ? MT : 1][2];

    const int tid  = threadIdx.x;
    const int wave = tid >> 6, lane = tid & 63;
    const int gm0 = blockIdx.x * MT;
    const int o0  = blockIdx.y * 128;
    const int mhalf = wave >> 1, ohalf = wave & 1;

    auto stage = [&](int kc, int h) {
        ushort_t* As = sbuf + h * HALF;
        ushort_t* Ws = As + MT * 64;
#pragma unroll
        for (int it = 0; it < 4; ++it) {          // W tile 128x64
            int s   = it * 256 + tid;
            int ln  = s & 63;
            int grp = s >> 6;
            int tile = grp >> 1, kst = grp & 1;
            int row = tile * 16 + (ln & 15);
            int kk  = kst * 32 + (ln >> 4) * 8;
            gld_lds16(&W[(size_t)(o0 + row) * K + kc + kk],
                      &Ws[(it * 256 + wave * 64) * 8]);
        }
#pragma unroll
        for (int it = 0; it < MT / 32; ++it) {    // A tile MTx64
            int s   = it * 256 + tid;
            int ln  = s & 63;
            int grp = s >> 6;
            int tile = grp >> 1, kst = grp & 1;
            int row = tile * 16 + (ln & 15);
            int kk  = kst * 32 + (ln >> 4) * 8;
            int ar = gm0 + row; if (ar >= M) ar = M - 1;
            gld_lds16(&A[(size_t)ar * lda + kc + kk],
                      &As[(it * 256 + wave * 64) * 8]);
        }
    };

    floatx4 acc[MI][4];
#pragma unroll
    for (int i = 0; i < MI; ++i)
#pragma unroll
        for (int j = 0; j < 4; ++j) acc[i][j] = (floatx4)(0.f);

    const int nk = K >> 6;
    stage(0, 0);
    __syncthreads();
    for (int t = 0; t < nk; ++t) {
        if (t + 1 < nk) stage((t + 1) * 64, (t + 1) & 1);
        const ushort_t* As = sbuf + (t & 1) * HALF;
        const ushort_t* Ws = As + MT * 64;
#pragma unroll
        for (int kst = 0; kst < 2; ++kst) {
            short8 af[MI], wf[4];
#pragma unroll
            for (int i = 0; i < MI; ++i) {
                int mt = mhalf * MI + i;
                af[i] = *(const short8*)&As[((mt * 2 + kst) * 64 + lane) * 8];
            }
#pragma unroll
            for (int j = 0; j < 4; ++j) {
                int ot = ohalf * 4 + j;
                wf[j] = *(const short8*)&Ws[((ot * 2 + kst) * 64 + lane) * 8];
            }
#pragma unroll
            for (int i = 0; i < MI; ++i)
#pragma unroll
                for (int j = 0; j < 4; ++j)
                    acc[i][j] = __builtin_amdgcn_mfma_f32_16x16x32_bf16(
                        af[i], wf[j], acc[i][j], 0, 0, 0);
        }
        __syncthreads();
    }

    // ---- epilogue ----
    ushort_t* B16 = sbuf;
    float*    B32 = (float*)sbuf;

    if (LN) {
#pragma unroll
        for (int j = 0; j < 4; ++j) {
            int oc = (ohalf * 4 + j) * 16 + (lane & 15);
            float bj = bias[oc];
#pragma unroll
            for (int i = 0; i < MI; ++i) {
                int rbase = gm0 + (mhalf * MI + i) * 16 + (lane >> 4) * 4;
#pragma unroll
                for (int r = 0; r < 4; ++r) {
                    int rowc = rbase + r; if (rowc >= M) rowc = M - 1;
                    float rv = resf && !OUTF ? bf2f(resb[(size_t)rowc * HID + oc])
                                             : 0.f;
                    rv = resb ? bf2f(resb[(size_t)rowc * HID + oc])
                              : resf ? resf[(size_t)rowc * HID + oc] : 0.f;
                    acc[i][j][r] += bj + rv;
                }
            }
        }
#pragma unroll
        for (int i = 0; i < MI; ++i) {
#pragma unroll
            for (int r = 0; r < 4; ++r) {
                float s1 = acc[i][0][r] + acc[i][1][r] + acc[i][2][r] + acc[i][3][r];
                float s2 = acc[i][0][r] * acc[i][0][r] + acc[i][1][r] * acc[i][1][r]
                         + acc[i][2][r] * acc[i][2][r] + acc[i][3][r] * acc[i][3][r];
                s1 += __shfl_xor(s1, 1); s1 += __shfl_xor(s1, 2);
                s1 += __shfl_xor(s1, 4); s1 += __shfl_xor(s1, 8);
                s2 += __shfl_xor(s2, 1); s2 += __shfl_xor(s2, 2);
                s2 += __shfl_xor(s2, 4); s2 += __shfl_xor(s2, 8);
                if ((lane & 15) == 0) {
                    int rl = (mhalf * MI + i) * 16 + (lane >> 4) * 4 + r;
                    pS[rl][ohalf] = s1;
                    pQ[rl][ohalf] = s2;
                }
            }
        }
        __syncthreads();
#pragma unroll
        for (int i = 0; i < MI; ++i) {
#pragma unroll
            for (int r = 0; r < 4; ++r) {
                int rl = (mhalf * MI + i) * 16 + (lane >> 4) * 4 + r;
                float S = pS[rl][0] + pS[rl][1];
                float Q = pQ[rl][0] + pQ[rl][1];
                float mu = S * (1.f / 128.f);
                float var = Q * (1.f / 128.f) - mu * mu;
                float rstd = rsqrtf(var + 1e-5f);
#pragma unroll
                for (int j = 0; j < 4; ++j) {
                    int oc = (ohalf * 4 + j) * 16 + (lane & 15);
                    acc[i][j][r] = (acc[i][j][r] - mu) * rstd * g[oc] + be[oc];
                }
            }
        }
        __syncthreads();
    }

    if (OUTF == 0 || (OUTF == 3 && blockIdx.y == 0)) {
#pragma unroll
        for (int i = 0; i < MI; ++i)
#pragma unroll
            for (int j = 0; j < 4; ++j) {
                int oc = (ohalf * 4 + j) * 16 + (lane & 15);
                float bj = LN ? 0.f : bias[o0 + oc];
#pragma unroll
                for (int r = 0; r < 4; ++r) {
                    int rl = (mhalf * MI + i) * 16 + (lane >> 4) * 4 + r;
                    float v = acc[i][j][r] + bj;
                    if (ACT) v = gelu_f(v);
                    B16[rl * 136 + oc] = f2bf(v);
                }
            }
        __syncthreads();
        const int oo = (OUTF == 3) ? 0 : o0;
#pragma unroll
        for (int p = 0; p < MT / 16; ++p) {
            int row = p * 16 + (tid >> 4);
            int ch  = tid & 15;
            if (gm0 + row < M) {
                short8 s = *(const short8*)&B16[row * 136 + ch * 8];
                *(short8*)&outb[(size_t)(gm0 + row) * ostride + oo + ch * 8] = s;
                if (LN && outf) {               // h fp8 image, pre-swizzled
                    unsigned u0 = 0, u1 = 0;
                    u0 = __builtin_amdgcn_cvt_pk_fp8_f32(
                             bf2f((ushort_t)s[0]), bf2f((ushort_t)s[1]), u0, false);
                    u0 = __builtin_amdgcn_cvt_pk_fp8_f32(
                             bf2f((ushort_t)s[2]), bf2f((ushort_t)s[3]), u0, true);
                    u1 = __builtin_amdgcn_cvt_pk_fp8_f32(
                             bf2f((ushort_t)s[4]), bf2f((ushort_t)s[5]), u1, false);
                    u1 = __builtin_amdgcn_cvt_pk_fp8_f32(
                             bf2f((ushort_t)s[6]), bf2f((ushort_t)s[7]), u1, true);
                    uint2 o; o.x = u0; o.y = u1;
                    unsigned char* h8 = (unsigned char*)outf;
                    *(uint2*)&h8[(size_t)(gm0 + row) * 128 +
                                 ((ch * 8) ^ ((row & 7) << 3))] = o;
                }
            }
        }
    } else if (OUTF == 3) {
        // fp8 e4m3 out with x64 scale, into interleaved kv chunks of 512B row
#pragma unroll
        for (int i = 0; i < MI; ++i)
#pragma unroll
            for (int j = 0; j < 4; ++j) {
                int oc = (ohalf * 4 + j) * 16 + (lane & 15);
                float bj = bias[o0 + oc];
#pragma unroll
                for (int r = 0; r < 4; ++r) {
                    int rl = (mhalf * MI + i) * 16 + (lane >> 4) * 4 + r;
                    float v = (acc[i][j][r] + bj) * KV_SCALE;
                    B16[rl * 136 + oc] = f2bf(v);
                }
            }
        __syncthreads();
        const int koff = (blockIdx.y - 1) * 8;
#pragma unroll
        for (int p = 0; p < MT / 16; ++p) {
            int row = p * 16 + (tid >> 4);
            int ch  = tid & 15;
            if (gm0 + row < M) {
                short8 s = *(const short8*)&B16[row * 136 + ch * 8];
                unsigned u0 = 0, u1 = 0;
                u0 = __builtin_amdgcn_cvt_pk_fp8_f32(
                         bf2f((ushort_t)s[0]), bf2f((ushort_t)s[1]), u0, false);
                u0 = __builtin_amdgcn_cvt_pk_fp8_f32(
                         bf2f((ushort_t)s[2]), bf2f((ushort_t)s[3]), u0, true);
                u1 = __builtin_amdgcn_cvt_pk_fp8_f32(
                         bf2f((ushort_t)s[4]), bf2f((ushort_t)s[5]), u1, false);
                u1 = __builtin_amdgcn_cvt_pk_fp8_f32(
                         bf2f((ushort_t)s[6]), bf2f((ushort_t)s[7]), u1, true);
                uint2 o; o.x = u0; o.y = u1;
                *(uint2*)((char*)outb + (size_t)(gm0 + row) * QKV_ROWB
                          + 256 + ch * 16 + koff) = o;
            }
        }
    } else {
#pragma unroll
        for (int p = 0; p < 2; ++p) {
            if (ohalf == p) {
#pragma unroll
                for (int i = 0; i < MI; ++i)
#pragma unroll
                    for (int j = 0; j < 4; ++j) {
                        int ocl = j * 16 + (lane & 15);
                        float bj = LN ? 0.f : bias[p * 64 + ocl];
#pragma unroll
                        for (int r = 0; r < 4; ++r) {
                            int rl = (mhalf * MI + i) * 16 + (lane >> 4) * 4 + r;
                            float v = acc[i][j][r] + bj;
                            if (ACT) v = gelu_f(v);
                            B32[rl * 68 + ocl] = v;
                        }
                    }
            }
            __syncthreads();
#pragma unroll
            for (int q = 0; q < MT / 16; ++q) {
                int row = q * 16 + (tid >> 4);
                int ch  = tid & 15;
                if (gm0 + row < M)
                    *(float4*)&outf[(size_t)(gm0 + row) * ostride + o0 + p * 64 + ch * 4] =
                        *(const float4*)&B32[row * 68 + ch * 4];
            }
            __syncthreads();
        }
    }
}

// ---------------- fp8 weights-resident fused FF ------------------------------
// 256 blocks x 512 thr. W1 (512x128) + W2 (128x512) fp8 resident in LDS
// (128KB, XOR-swizzled via pre-swizzled global images). Grid-stride over
// 64-row tiles: stage 8KB h-fp8; per ff-half: GEMM1 -> GELU -> a1 fp8 LDS ->
// GEMM2 accumulate. LN2 from bf16 hb residual. Direct f32 store.
__global__ __launch_bounds__(512)
void ff8_kernel(const unsigned char* __restrict__ hf8,  // [M][128] fp8 pre-swz
                const ushort_t* __restrict__ hb,        // [M][128] bf16
                const unsigned char* __restrict__ w1f8,
                const unsigned char* __restrict__ w2f8,
                const float* __restrict__ b1, const float* __restrict__ b2,
                const float* __restrict__ g, const float* __restrict__ be,
                float* __restrict__ out, int M, int ntiles)
{
    __shared__ __align__(16) unsigned char W1s[65536];
    __shared__ __align__(16) unsigned char W2s[65536];
    __shared__ __align__(16) unsigned char Hs8[8192];
    __shared__ __align__(16) unsigned char A1s[16384];   // 64 x 256 (half)
    __shared__ float pS[64][4];
    __shared__ float pQ[64][4];

    const int tid  = threadIdx.x;
    const int wave = tid >> 6, lane = tid & 63;
    const int wm = wave >> 2;        // 0..1: rows [wm*32, +32)
    const int wn = wave & 3;         // 0..3: col group
    const int l15 = lane & 15, l4 = lane >> 4;

    // ---- stage resident weights (once) ----
#pragma unroll
    for (int it = 0; it < 8; ++it)
        gld_lds16(w1f8 + (it * 512 + tid) * 16,
                  W1s + (it * 512 + wave * 64) * 16);
#pragma unroll
    for (int it = 0; it < 8; ++it)
        gld_lds16(w2f8 + (it * 512 + tid) * 16,
                  W2s + (it * 512 + wave * 64) * 16);

    for (int t = blockIdx.x; t < ntiles; t += gridDim.x) {
        const int gm0 = t * 64;
        {   // stage h tile fp8: 64 x 128B (linear copy; rows clamped at src)
            int rr = gm0 + (tid >> 3); if (rr >= M) rr = M - 1;
            gld_lds16(hf8 + (size_t)rr * 128 + (tid & 7) * 16,
                      Hs8 + (wave * 64 + lane) * 16);
        }
        __syncthreads();                 // weights (1st iter) + Hs8 + A1s free

        floatx4 acc2[2][2];
#pragma unroll
        for (int i = 0; i < 2; ++i)
#pragma unroll
            for (int j = 0; j < 2; ++j) acc2[i][j] = (floatx4)(0.f);

        for (int hc = 0; hc < 2; ++hc) {
            // ---- GEMM1: h(64x128) @ W1half^T -> acc1 (this wave: 64 cols) ----
            floatx4 acc1[2][4];
#pragma unroll
            for (int i = 0; i < 2; ++i)
#pragma unroll
                for (int j = 0; j < 4; ++j) acc1[i][j] = (floatx4)(0.f);
#pragma unroll
            for (int ks = 0; ks < 4; ++ks) {
                int k = ks * 32 + l4 * 8;
                long av[2];
#pragma unroll
                for (int i = 0; i < 2; ++i) {
                    int row = (wm * 2 + i) * 16 + l15;
                    av[i] = *(const long*)&Hs8[row * 128 + FF_SWZ(row, k)];
                }
#pragma unroll
                for (int j = 0; j < 4; ++j) {
                    int fc = hc * 256 + wn * 64 + j * 16 + l15;
                    long bv = *(const long*)&W1s[(size_t)fc * 128 + FF_SWZ(fc, k)];
#pragma unroll
                    for (int i = 0; i < 2; ++i)
                        acc1[i][j] = __builtin_amdgcn_mfma_f32_16x16x32_fp8_fp8(
                            av[i], bv, acc1[i][j], 0, 0, 0);
                }
            }
            // ---- GELU -> a1 fp8 (swizzled byte writes) ----
            float b1v[4];
#pragma unroll
            for (int j = 0; j < 4; ++j)
                b1v[j] = b1[hc * 256 + wn * 64 + j * 16 + l15];
#pragma unroll
            for (int i = 0; i < 2; ++i)
#pragma unroll
                for (int j = 0; j < 4; ++j) {
                    int col = wn * 64 + j * 16 + l15;   // k-index within half
#pragma unroll
                    for (int r = 0; r < 4; ++r) {
                        int row = (wm * 2 + i) * 16 + l4 * 4 + r;
                        float v = acc1[i][j][r] * G1_DESCALE + b1v[j];
                        v = gelu_f(v) * A1_SCALE;
                        unsigned u = __builtin_amdgcn_cvt_pk_fp8_f32(v, v, 0, false);
                        A1s[row * 256 + FF_SWZ(row, col)] = (unsigned char)u;
                    }
                }
            __syncthreads();             // a1 visible
            // ---- GEMM2 accumulate: a1(64x256) @ W2[:, hc*256..]^T ----
#pragma unroll
            for (int ks = 0; ks < 8; ++ks) {
                int k = ks * 32 + l4 * 8;
                long av[2];
#pragma unroll
                for (int i = 0; i < 2; ++i) {
                    int row = (wm * 2 + i) * 16 + l15;
                    av[i] = *(const long*)&A1s[row * 256 + FF_SWZ(row, k)];
                }
#pragma unroll
                for (int j = 0; j < 2; ++j) {
                    int oc = wn * 32 + j * 16 + l15;
                    long bv = *(const long*)&W2s[(size_t)oc * 512 + hc * 256 +
                                                 FF_SWZ(oc, k)];
#pragma unroll
                    for (int i = 0; i < 2; ++i)
                        acc2[i][j] = __builtin_amdgcn_mfma_f32_16x16x32_fp8_fp8(
                            av[i], bv, acc2[i][j], 0, 0, 0);
                }
            }
            __syncthreads();             // a1 free for next half
        }

        // ---- LN2: descale + bias + residual(hb), stats, normalize, store ----
        float b2v[2];
#pragma unroll
        for (int j = 0; j < 2; ++j) b2v[j] = b2[wn * 32 + j * 16 + l15];
#pragma unroll
        for (int i = 0; i < 2; ++i)
#pragma unroll
            for (int j = 0; j < 2; ++j) {
                int oc = wn * 32 + j * 16 + l15;
#pragma unroll
                for (int r = 0; r < 4; ++r) {
                    int rowg = gm0 + (wm * 2 + i) * 16 + l4 * 4 + r;
                    if (rowg >= M) rowg = M - 1;
                    acc2[i][j][r] = acc2[i][j][r] * G2_DESCALE + b2v[j]
                                  + bf2f(hb[(size_t)rowg * HID + oc]);
                }
            }
#pragma unroll
        for (int i = 0; i < 2; ++i) {
#pragma unroll
            for (int r = 0; r < 4; ++r) {
                float s1 = acc2[i][0][r] + acc2[i][1][r];
                float s2 = acc2[i][0][r] * acc2[i][0][r]
                         + acc2[i][1][r] * acc2[i][1][r];
                s1 += __shfl_xor(s1, 1); s1 += __shfl_xor(s1, 2);
                s1 += __shfl_xor(s1, 4); s1 += __shfl_xor(s1, 8);
                s2 += __shfl_xor(s2, 1); s2 += __shfl_xor(s2, 2);
                s2 += __shfl_xor(s2, 4); s2 += __shfl_xor(s2, 8);
                if (l15 == 0) {
                    int rl = (wm * 2 + i) * 16 + l4 * 4 + r;
                    pS[rl][wn] = s1;
                    pQ[rl][wn] = s2;
                }
            }
        }
        __syncthreads();
#pragma unroll
        for (int i = 0; i < 2; ++i) {
#pragma unroll
            for (int r = 0; r < 4; ++r) {
                int rl = (wm * 2 + i) * 16 + l4 * 4 + r;
                float S = pS[rl][0] + pS[rl][1] + pS[rl][2] + pS[rl][3];
                float Q = pQ[rl][0] + pQ[rl][1] + pQ[rl][2] + pQ[rl][3];
                float mu = S * (1.f / 128.f);
                float var = Q * (1.f / 128.f) - mu * mu;
                float rstd = rsqrtf(var + 1e-5f);
                if (gm0 + rl < M) {
#pragma unroll
                    for (int j = 0; j < 2; ++j) {
                        int oc = wn * 32 + j * 16 + l15;
                        out[(size_t)(gm0 + rl) * HID + oc] =
                            (acc2[i][j][r] - mu) * rstd * g[oc] + be[oc];
                    }
                }
            }
        }
        // next tile's Hs8 stage + barrier orders pS/A1s reuse
    }
}

// ---------------- counting-sort scan chain ----------------------------------
__global__ __launch_bounds__(256)
void scan1_kernel(const int* __restrict__ cnt, int* __restrict__ parts, int N)
{
    __shared__ int sd[256];
    int t = threadIdx.x;
    int base = blockIdx.x * 1024 + t * 4;
    int s = 0;
#pragma unroll
    for (int j = 0; j < 4; ++j) if (base + j < N) s += cnt[base + j];
    sd[t] = s; __syncthreads();
    for (int off = 128; off; off >>= 1) {
        if (t < off) sd[t] += sd[t + off];
        __syncthreads();
    }
    if (t == 0) parts[blockIdx.x] = sd[0];
}

__global__ __launch_bounds__(256)
void scan2_kernel(const int* __restrict__ parts, int* __restrict__ poff, int nb)
{
    __shared__ int sd[256];
    int t = threadIdx.x;
    int v = (t < nb) ? parts[t] : 0;
    sd[t] = v; __syncthreads();
    for (int off = 1; off < 256; off <<= 1) {
        int u = (t >= off) ? sd[t - off] : 0;
        __syncthreads();
        sd[t] += u;
        __syncthreads();
    }
    if (t < nb) poff[t] = sd[t] - v;   // exclusive
}

__global__ __launch_bounds__(256)
void scan3_kernel(const int* __restrict__ cnt, const int* __restrict__ poff,
                  int* __restrict__ rp, int N)
{
    __shared__ int sd[256];
    int t = threadIdx.x;
    int base = blockIdx.x * 1024 + t * 4;
    int v0 = (base + 0 < N) ? cnt[base + 0] : 0;
    int v1 = (base + 1 < N) ? cnt[base + 1] : 0;
    int v2 = (base + 2 < N) ? cnt[base + 2] : 0;
    int v3 = (base + 3 < N) ? cnt[base + 3] : 0;
    int s = v0 + v1 + v2 + v3;
    sd[t] = s; __syncthreads();
    for (int off = 1; off < 256; off <<= 1) {
        int u = (t >= off) ? sd[t - off] : 0;
        __syncthreads();
        sd[t] += u;
        __syncthreads();
    }
    int o = poff[blockIdx.x] + sd[t] - s;
    if (base + 0 < N) rp[base + 0] = o;
    if (base + 1 < N) rp[base + 1] = o + v0;
    if (base + 2 < N) rp[base + 2] = o + v0 + v1;
    if (base + 3 < N) rp[base + 3] = o + v0 + v1 + v2;
}

// cohort scatter: blockIdx.x & 7 keys the XCD; each cohort owns 1/8 of nodes.
__global__ __launch_bounds__(256)
void scatter_kernel(const int* __restrict__ src, const int* __restrict__ dst,
                    int* __restrict__ rp, int* __restrict__ ssrc, int E, int N)
{
    int coh = blockIdx.x & 7;
    int bc  = blockIdx.x >> 3;
    int rr  = (N + 7) >> 3;
    int nlo = coh * rr;
    int nhi = nlo + rr; if (nhi > N) nhi = N;
    int stride = (gridDim.x >> 3) * 256;
    for (int e = bc * 256 + threadIdx.x; e < E; e += stride) {
        int d = dst[e];
        if (d >= nlo && d < nhi) {
            int pos = atomicAdd(&rp[d], 1);
            ssrc[pos] = src[e];
        }
    }
}

// ---------------- fused attention: 4 edges per wave-step ---------------------
__global__ __launch_bounds__(256)
void attn_fused_kernel(const ushort_t* __restrict__ qkvb, const int* __restrict__ rp,
                       const int* __restrict__ ssrc, ushort_t* __restrict__ aggb, int N)
{
    int wave = threadIdx.x >> 6, lane = threadIdx.x & 63;
    int n = blockIdx.x * 4 + wave;
    if (n >= N) return;
    int grp = lane >> 4;            // 0..3 edge slot
    int cb  = (lane & 15) * 16;     // byte offset of this lane's 16B chunk
    const char* base = (const char*)qkvb;

    short8 qv = *(const short8*)(base + n * QKV_ROWB + cb);
    float q[8];
#pragma unroll
    for (int j = 0; j < 8; ++j) q[j] = bf2f((ushort_t)qv[j]) * (0.25f / KV_SCALE);

    int r0 = n ? rp[n - 1] : 0;
    int r1 = rp[n];
    float acc[8] = {0.f, 0.f, 0.f, 0.f, 0.f, 0.f, 0.f, 0.f};
    float l = 0.f;

    int r = r0;
    for (; r + 8 <= r1; r += 8) {
        int s0 = ssrc[r + grp];
        int s1 = ssrc[r + 4 + grp];
        uint4 kv0 = *(const uint4*)(base + s0 * QKV_ROWB + 256 + cb);
        uint4 kv1 = *(const uint4*)(base + s1 * QKV_ROWB + 256 + cb);

        f32x2 a0 = __builtin_amdgcn_cvt_pk_f32_fp8(kv0.x, false);
        f32x2 a1 = __builtin_amdgcn_cvt_pk_f32_fp8(kv0.x, true);
        f32x2 a2 = __builtin_amdgcn_cvt_pk_f32_fp8(kv0.y, false);
        f32x2 a3 = __builtin_amdgcn_cvt_pk_f32_fp8(kv0.y, true);
        f32x2 b0 = __builtin_amdgcn_cvt_pk_f32_fp8(kv1.x, false);
        f32x2 b1 = __builtin_amdgcn_cvt_pk_f32_fp8(kv1.x, true);
        f32x2 b2 = __builtin_amdgcn_cvt_pk_f32_fp8(kv1.y, false);
        f32x2 b3 = __builtin_amdgcn_cvt_pk_f32_fp8(kv1.y, true);

        float p0 = 0.f, p1 = 0.f;
        p0 = fmaf(q[0], a0.x, p0); p0 = fmaf(q[1], a0.y, p0);
        p0 = fmaf(q[2], a1.x, p0); p0 = fmaf(q[3], a1.y, p0);
        p0 = fmaf(q[4], a2.x, p0); p0 = fmaf(q[5], a2.y, p0);
        p0 = fmaf(q[6], a3.x, p0); p0 = fmaf(q[7], a3.y, p0);
        p1 = fmaf(q[0], b0.x, p1); p1 = fmaf(q[1], b0.y, p1);
        p1 = fmaf(q[2], b1.x, p1); p1 = fmaf(q[3], b1.y, p1);
        p1 = fmaf(q[4], b2.x, p1); p1 = fmaf(q[5], b2.y, p1);
        p1 = fmaf(q[6], b3.x, p1); p1 = fmaf(q[7], b3.y, p1);

        p0 += __shfl_xor(p0, 1);
        p1 += __shfl_xor(p1, 1);
        float e0 = __expf(p0), e1 = __expf(p1);
        l += e0 + e1;

        f32x2 v0 = __builtin_amdgcn_cvt_pk_f32_fp8(kv0.z, false);
        f32x2 v1 = __builtin_amdgcn_cvt_pk_f32_fp8(kv0.z, true);
        f32x2 v2 = __builtin_amdgcn_cvt_pk_f32_fp8(kv0.w, false);
        f32x2 v3 = __builtin_amdgcn_cvt_pk_f32_fp8(kv0.w, true);
        f32x2 w0 = __builtin_amdgcn_cvt_pk_f32_fp8(kv1.z, false);
        f32x2 w1 = __builtin_amdgcn_cvt_pk_f32_fp8(kv1.z, true);
        f32x2 w2 = __builtin_amdgcn_cvt_pk_f32_fp8(kv1.w, false);
        f32x2 w3 = __builtin_amdgcn_cvt_pk_f32_fp8(kv1.w, true);

        acc[0] = fmaf(e0, v0.x, acc[0]); acc[1] = fmaf(e0, v0.y, acc[1]);
        acc[2] = fmaf(e0, v1.x, acc[2]); acc[3] = fmaf(e0, v1.y, acc[3]);
        acc[4] = fmaf(e0, v2.x, acc[4]); acc[5] = fmaf(e0, v2.y, acc[5]);
        acc[6] = fmaf(e0, v3.x, acc[6]); acc[7] = fmaf(e0, v3.y, acc[7]);
        acc[0] = fmaf(e1, w0.x, acc[0]); acc[1] = fmaf(e1, w0.y, acc[1]);
        acc[2] = fmaf(e1, w1.x, acc[2]); acc[3] = fmaf(e1, w1.y, acc[3]);
        acc[4] = fmaf(e1, w2.x, acc[4]); acc[5] = fmaf(e1, w2.y, acc[5]);
        acc[6] = fmaf(e1, w3.x, acc[6]); acc[7] = fmaf(e1, w3.y, acc[7]);
    }
    for (; r < r1; r += 4) {
        int e = r + grp;
        int s = ssrc[(e < r1) ? e : r0];
        uint4 kv = *(const uint4*)(base + s * QKV_ROWB + 256 + cb);
        f32x2 a0 = __builtin_amdgcn_cvt_pk_f32_fp8(kv.x, false);
        f32x2 a1 = __builtin_amdgcn_cvt_pk_f32_fp8(kv.x, true);
        f32x2 a2 = __builtin_amdgcn_cvt_pk_f32_fp8(kv.y, false);
        f32x2 a3 = __builtin_amdgcn_cvt_pk_f32_fp8(kv.y, true);
        float p = 0.f;
        p = fmaf(q[0], a0.x, p); p = fmaf(q[1], a0.y, p);
        p = fmaf(q[2], a1.x, p); p = fmaf(q[3], a1.y, p);
        p = fmaf(q[4], a2.x, p); p = fmaf(q[5], a2.y, p);
        p = fmaf(q[6], a3.x, p); p = fmaf(q[7], a3.y, p);
        p += __shfl_xor(p, 1);
        float ea = (e < r1) ? __expf(p) : 0.f;
        l += ea;
        f32x2 v0 = __builtin_amdgcn_cvt_pk_f32_fp8(kv.z, false);
        f32x2 v1 = __builtin_amdgcn_cvt_pk_f32_fp8(kv.z, true);
        f32x2 v2 = __builtin_amdgcn_cvt_pk_f32_fp8(kv.w, false);
        f32x2 v3 = __builtin_amdgcn_cvt_pk_f32_fp8(kv.w, true);
        acc[0] = fmaf(ea, v0.x, acc[0]); acc[1] = fmaf(ea, v0.y, acc[1]);
        acc[2] = fmaf(ea, v1.x, acc[2]); acc[3] = fmaf(ea, v1.y, acc[3]);
        acc[4] = fmaf(ea, v2.x, acc[4]); acc[5] = fmaf(ea, v2.y, acc[5]);
        acc[6] = fmaf(ea, v3.x, acc[6]); acc[7] = fmaf(ea, v3.y, acc[7]);
    }

#pragma unroll
    for (int j = 0; j < 8; ++j) {
        acc[j] += __shfl_xor(acc[j], 16);
        acc[j] += __shfl_xor(acc[j], 32);
    }
    l += __shfl_xor(l, 16);
    l += __shfl_xor(l, 32);
    float inv = KV_INV_SCALE / (l + 1e-16f);
    if (grp == 0) {
        short8 o;
#pragma unroll
        for (int j = 0; j < 8; ++j) o[j] = (short)f2bf(acc[j] * inv);
        *(short8*)((char*)aggb + n * 256 + cb) = o;
    }
}

// ============================================================================
extern "C" void kernel_launch(void* const* d_in, const int* in_sizes, int n_in,
                              void* d_out, int out_size, void* d_ws, size_t ws_size,
                              hipStream_t stream)
{
    const float* x  = (const float*)d_in[0];
    const int*   ei = (const int*)d_in[1];
    const float* Wq = (const float*)d_in[2];
    const float* bq = (const float*)d_in[3];
    const float* Wk = (const float*)d_in[4];
    const float* bk = (const float*)d_in[5];
    const float* Wv = (const float*)d_in[6];
    const float* bv = (const float*)d_in[7];
    const float* Wo = (const float*)d_in[8];
    const float* bo = (const float*)d_in[9];
    const float* W1 = (const float*)d_in[10];
    const float* b1 = (const float*)d_in[11];
    const float* W2 = (const float*)d_in[12];
    const float* b2 = (const float*)d_in[13];
    const float* g1 = (const float*)d_in[14];
    const float* be1= (const float*)d_in[15];
    const float* g2 = (const float*)d_in[16];
    const float* be2= (const float*)d_in[17];
    float* out = (float*)d_out;

    const int N = in_sizes[0] / HID;      // 50000
    const int E = in_sizes[1] / 2;        // 800000
    const int* srcp = ei;
    const int* dstp = ei + E;

    const size_t NH = (size_t)N * HID;    // 6.4M
    float* wsf = (float*)d_ws;

    // ---- workspace layout (f32 units) ----
    ushort_t* xb   = (ushort_t*)wsf;                  // [0, 0.5NH)  dies after QKV
    ushort_t* qkvb = (ushort_t*)(wsf + NH / 2);       // [0.5, 1.5)  dies after attn
    ushort_t* aggb = (ushort_t*)(wsf + 2 * NH);       // [2.0, 2.5)  dies after Wo
    ushort_t* hb   = (ushort_t*)wsf;                  // [0, 0.5)    overlays dead xb
    unsigned char* hf8 = (unsigned char*)(wsf + NH / 2);      // overlays dead qkvb
    unsigned char* w1f8 = (unsigned char*)(wsf + NH + NH / 2); // [1.5,2.0) gap
    unsigned char* w2f8 = w1f8 + 65536;

    ushort_t* wts  = (ushort_t*)(wsf + 2 * NH + NH / 2);  // 196608 ushort reserved
    float*    bqkv = (float*)(wts + 196608);              // 384 f32
    int*      rp   = (int*)(bqkv + 384);                  // N+1
    int*      cnt  = rp + (N + 1);                        // N
    int*      poff = cnt + N;                             // 256
    int*      parts= poff + 256;                          // 256
    int*      ssrc = parts + 256;                         // E

    // ---- prep (+fused degree count; cnt zeroed first) ----
    hipMemsetAsync(cnt, 0, N * sizeof(int), stream);
    const int xpairs = (int)(NH / 2);
    const int ptot   = xpairs + 32768 + 384 + 16384 + E;
    prep_kernel<<<(ptot + 255) / 256, 256, 0, stream>>>(
        x, Wq, Wk, Wv, Wo, W1, W2, bq, bk, bv, dstp, cnt, E,
        xb, wts, bqkv, w1f8, w2f8, xpairs);

    // ---- counting sort of edges by dst ----
    const int nb = (N + 1023) / 1024;   // 49
    scan1_kernel<<<nb, 256, 0, stream>>>(cnt, parts, N);
    scan2_kernel<<<1, 256, 0, stream>>>(parts, poff, nb);
    scan3_kernel<<<nb, 256, 0, stream>>>(cnt, poff, rp, N);
    scatter_kernel<<<2048, 256, 0, stream>>>(srcp, dstp, rp, ssrc, E, N);

    const int gx64 = (N + 63) / 64;     // 782

    // ---- merged QKV: y=0 -> q bf16, y=1/2 -> k/v fp8 ----
    gemm_t<64, 0, 0, 3><<<dim3(gx64, 3), 256, 0, stream>>>(
        xb, HID, N, wts, HID, bqkv, nullptr, qkvb, 256,
        nullptr, nullptr, nullptr, nullptr);

    // ---- fused attention ----
    attn_fused_kernel<<<(N + 3) / 4, 256, 0, stream>>>(qkvb, rp, ssrc, aggb, N);

    // ---- Wo + residual(x) + LN1 -> hb (bf16) + hf8 (fp8 pre-swizzled) ----
    gemm_t<64, 0, 1, 0><<<dim3(gx64, 1), 256, 0, stream>>>(
        aggb, HID, N, wts + 49152, HID, bo, (float*)hf8, hb, HID,
        x, nullptr, g1, be1);

    // ---- fp8 weights-resident FF1+GELU+FF2+residual+LN2 -> out (f32) ----
    ff8_kernel<<<256, 512, 0, stream>>>(
        hf8, hb, w1f8, w2f8, b1, b2, g2, be2, out, N, gx64);
}